// Round 12
// baseline (212.705 us; speedup 1.0000x reference)
//
#include <hip/hip_runtime.h>
#include <math.h>

// MaskedBalancedBCELoss — hard-negative mining via count-histogram select.
//
// R22: RAMP-CURVE PROBE, kernels byte-identical to R20/R21 (best: 181.4).
// R21 verdict: k1's 60-62us is COLD-CLOCK bound, not balance/structure:
//   per-CU request cap ~10.3 B/cy/CU (fixed); 2.4GHz -> 6.33 TB/s (all
//   late-position kernels); ~1.03GHz -> 2.6 TB/s (every first-position
//   kernel, 60-84us across ALL structures). Harness's ~1ms reset gap
//   de-ramps the clock before each iteration.
// Open question: does the clock ramp engage at kernel boundaries / within
// our ~73us busy window? Evidence brackets transition in (0, ~77us] busy.
// R22: split k1 into 3 POINTER-SHIFTED relaunches of the identical kernel
// (b=800, n4 = 16S exactly): chunks 4S | 4S | 8S, disjoint wredux slots.
// Host-only change; zero codegen risk.
// Decode by chunk durations: 16/16/31 -> null, cold-clock roofline ->
// declare next round. 16/6/12 -> boundary ramp -> shrink chunk1 next.
// 16/16/12 -> tau~35us busy.

#define NBINS1 4096

#define LN2F 0.69314718055994530942f

__device__ __forceinline__ double bin_mid(unsigned b) {
  return (double)__uint_as_float((b << 19) | 0x40000u);
}

// Branchless per-element processing (loss bit-identical to R10..R21).
__device__ __forceinline__ void proc1(float p, float g, float m, unsigned ln,
                                      unsigned& pc, unsigned& nc,
                                      float& psumf, unsigned* __restrict__ hc) {
  bool gpos = (g != 0.0f);
  bool valid = (m != 0.0f);
  bool ispos = valid && gpos;
  bool isneg = valid && !gpos;
  float x = gpos ? p : 1.0f - p;
  float loss = -fmaxf(__log2f(x) * LN2F, -100.0f);
  pc += ispos ? 1u : 0u;
  nc += isneg ? 1u : 0u;
  psumf += ispos ? loss : 0.0f;
  unsigned b = isneg ? (__float_as_uint(loss) >> 19) : (NBINS1 + ln);
  atomicAdd(&hc[b], 1u);
}

// ---------------- Kernel 1: dg_kb1-shaped hot kernel -----------------------
// Covers [0, nfull4) float4s of the given base pointers exactly (host
// guarantees nfull4 % (4*S) == 0). Byte-identical to R20/R21's k1.
// Chunking is done by POINTER SHIFT on the host — do not add code here.
extern "C" __global__ void __launch_bounds__(256, 4)
k1_hist(const float* __restrict__ pred, const float* __restrict__ gt,
        const float* __restrict__ mask, unsigned* __restrict__ hist1,
        float4* __restrict__ wredux, int nfull4) {
  __shared__ unsigned h[NBINS1 + 64];
  for (int i = threadIdx.x; i < NBINS1 + 64; i += blockDim.x) h[i] = 0u;
  __syncthreads();

  const float4* p4 = (const float4*)pred;
  const float4* g4 = (const float4*)gt;
  const float4* m4 = (const float4*)mask;
  int gtid = blockIdx.x * blockDim.x + threadIdx.x;
  int S = gridDim.x * blockDim.x;
  unsigned ln = threadIdx.x & 63;

  unsigned pc = 0, nc = 0;
  float psumf = 0.0f;
  for (int rep = 0; rep < 1; ++rep) {
    for (int i = gtid; i + 3 * S < nfull4; i += 4 * S) {
      int jb = i + rep;
      float4 pv0 = p4[jb], pv1 = p4[jb + S], pv2 = p4[jb + 2 * S], pv3 = p4[jb + 3 * S];
      float4 gv0 = g4[jb], gv1 = g4[jb + S], gv2 = g4[jb + 2 * S], gv3 = g4[jb + 3 * S];
      float4 mv0 = m4[jb], mv1 = m4[jb + S], mv2 = m4[jb + 2 * S], mv3 = m4[jb + 3 * S];
      float pa[16] = {pv0.x, pv0.y, pv0.z, pv0.w, pv1.x, pv1.y, pv1.z, pv1.w,
                      pv2.x, pv2.y, pv2.z, pv2.w, pv3.x, pv3.y, pv3.z, pv3.w};
      float ga[16] = {gv0.x, gv0.y, gv0.z, gv0.w, gv1.x, gv1.y, gv1.z, gv1.w,
                      gv2.x, gv2.y, gv2.z, gv2.w, gv3.x, gv3.y, gv3.z, gv3.w};
      float ma[16] = {mv0.x, mv0.y, mv0.z, mv0.w, mv1.x, mv1.y, mv1.z, mv1.w,
                      mv2.x, mv2.y, mv2.z, mv2.w, mv3.x, mv3.y, mv3.z, mv3.w};
#pragma unroll
      for (int j = 0; j < 16; j++) {
        bool gpos = (ga[j] != 0.0f);
        bool valid = (ma[j] != 0.0f);
        bool ispos = valid && gpos;
        bool isneg = valid && !gpos;
        float x = gpos ? pa[j] : 1.0f - pa[j];
        float loss = -fmaxf(__log2f(x) * LN2F, -100.0f);
        pc += ispos ? 1u : 0u;
        nc += isneg ? 1u : 0u;
        psumf += ispos ? loss : 0.0f;
        unsigned b = isneg ? (__float_as_uint(loss) >> 19) : (NBINS1 + ln);
        atomicAdd(&h[b], 1u);   // unconditional: no exec-mask branch
      }
    }
  }

  // epilogue, dg_kb1-shaped: f32 shuffle reduce + ONE plain store per wave.
  float fpc = (float)pc, fnc = (float)nc;
  for (int off = 32; off > 0; off >>= 1) {
    fpc += __shfl_down(fpc, off);
    fnc += __shfl_down(fnc, off);
    psumf += __shfl_down(psumf, off);
  }
  if (ln == 0)
    wredux[blockIdx.x * 4 + (threadIdx.x >> 6)] = make_float4(fpc, fnc, psumf, 0.0f);
  __syncthreads();   // all LDS histogram atomics complete
  for (int b = threadIdx.x; b < NBINS1; b += blockDim.x) {
    unsigned c = h[b];
    if (c) atomicAdd(&hist1[b], c);
  }
}

// -------- k2_tail: cold coverage for generic n (not launched for this shape)
extern "C" __global__ void __launch_bounds__(256, 4)
k2_tail(const float* __restrict__ pred, const float* __restrict__ gt,
        const float* __restrict__ mask, unsigned* __restrict__ hist1,
        float4* __restrict__ wredux, int start4, int n4, int n, int wbase) {
  __shared__ unsigned h[NBINS1 + 64];
  for (int i = threadIdx.x; i < NBINS1 + 64; i += blockDim.x) h[i] = 0u;
  __syncthreads();

  const float4* p4 = (const float4*)pred;
  const float4* g4 = (const float4*)gt;
  const float4* m4 = (const float4*)mask;
  int gtid = blockIdx.x * blockDim.x + threadIdx.x;
  int S = gridDim.x * blockDim.x;
  unsigned ln = threadIdx.x & 63;

  unsigned pc = 0, nc = 0;
  float psumf = 0.0f;
  for (int i = start4 + gtid; i < n4; i += S) {
    float4 pv = p4[i], gv = g4[i], mv = m4[i];
    proc1(pv.x, gv.x, mv.x, ln, pc, nc, psumf, h);
    proc1(pv.y, gv.y, mv.y, ln, pc, nc, psumf, h);
    proc1(pv.z, gv.z, mv.z, ln, pc, nc, psumf, h);
    proc1(pv.w, gv.w, mv.w, ln, pc, nc, psumf, h);
  }
  for (int t = n4 * 4 + gtid; t < n; t += S) {
    proc1(pred[t], gt[t], mask[t], ln, pc, nc, psumf, h);
  }

  float fpc = (float)pc, fnc = (float)nc;
  for (int off = 32; off > 0; off >>= 1) {
    fpc += __shfl_down(fpc, off);
    fnc += __shfl_down(fnc, off);
    psumf += __shfl_down(psumf, off);
  }
  if (ln == 0)
    wredux[wbase + blockIdx.x * 4 + (threadIdx.x >> 6)] = make_float4(fpc, fnc, psumf, 0.0f);
  __syncthreads();
  for (int b = threadIdx.x; b < NBINS1; b += blockDim.x) {
    unsigned c = h[b];
    if (c) atomicAdd(&hist1[b], c);
  }
}

// ---------- Kernel 5: wredux reduce + select + midpoint neg_sum ------------
extern "C" __global__ void __launch_bounds__(256)
k5_final(const unsigned* __restrict__ hist1, const float4* __restrict__ wredux,
         int nwaves, float* __restrict__ out) {
  const int T = 256, CH = NBINS1 / T;  // 16 bins per thread
  __shared__ unsigned long long sarr[T];
  __shared__ unsigned long long sk;
  __shared__ unsigned sB, skrem;
  __shared__ double sred[4];
  __shared__ double rpc[T], rnc[T], rps[T];
  __shared__ unsigned long long s_pos;
  __shared__ double s_psum;
  int t = threadIdx.x;
  int wv = t >> 6, ln = t & 63;

  // ---- reduce per-wave partials (exact: counts are integers in f32) ----
  double tpc = 0.0, tnc = 0.0, tps = 0.0;
  for (int i = t; i < nwaves; i += T) {
    float4 v = wredux[i];
    tpc += (double)v.x; tnc += (double)v.y; tps += (double)v.z;
  }
  rpc[t] = tpc; rnc[t] = tnc; rps[t] = tps;
  __syncthreads();
  for (int off = T / 2; off > 0; off >>= 1) {
    if (t < off) { rpc[t] += rpc[t + off]; rnc[t] += rnc[t + off]; rps[t] += rps[t + off]; }
    __syncthreads();
  }

  unsigned cnt[CH];
  unsigned long long tot = 0;
  for (int j = 0; j < CH; j++) { cnt[j] = hist1[t * CH + j]; tot += cnt[j]; }
  sarr[t] = tot;
  if (t == 0) {
    sB = 0xFFFFFFFFu; skrem = 0u;
    unsigned long long pos = (unsigned long long)(rpc[0] + 0.5);
    unsigned long long negtot = (unsigned long long)(rnc[0] + 0.5);
    unsigned long long k = 0;
    if (pos > 0) {               // FALLBACK_NEG=0 when pos==0
      k = pos * 3ull;            // floor(pos*3.0), exact in integer
      if (k > negtot) k = negtot;
    }
    sk = k;
    s_pos = pos;
    s_psum = rps[0];
  }
  __syncthreads();
  // inclusive suffix scan: sarr[t] = sum over threads >= t
  for (int off = 1; off < T; off <<= 1) {
    unsigned long long v = (t + off < T) ? sarr[t + off] : 0ull;
    __syncthreads();
    sarr[t] += v;
    __syncthreads();
  }
  unsigned long long k = sk;
  if (k > 0) {
    unsigned long long above = sarr[t] - tot;
    if (above < k && sarr[t] >= k) {
      unsigned long long cum = above;
      for (int j = CH - 1; j >= 0; j--) {
        if (cum + (unsigned long long)cnt[j] >= k) {
          sB = (unsigned)(t * CH + j);
          skrem = (unsigned)(k - cum);
          break;
        }
        cum += cnt[j];
      }
    }
  }
  __syncthreads();
  unsigned B = sB;

  // neg_sum (midpoint model): each thread sums its own bins above B
  double s = 0.0;
  if (B != 0xFFFFFFFFu) {
    for (int j = 0; j < CH; j++) {
      unsigned bi = (unsigned)(t * CH + j);
      if (bi > B && cnt[j]) s += (double)cnt[j] * bin_mid(bi);
    }
  }
  for (int off = 32; off > 0; off >>= 1) s += __shfl_down(s, off);
  if (ln == 0) sred[wv] = s;
  __syncthreads();
  if (t == 0) {
    double neg_sum = sred[0] + sred[1] + sred[2] + sred[3];
    if (skrem > 0 && B != 0xFFFFFFFFu)
      neg_sum += (double)skrem * bin_mid(B);
    double denom = (double)s_pos + (double)k + 1e-6;
    out[0] = (float)((s_psum + neg_sum) / denom);
  }
}

// ---------------------------------------------------------------------------
extern "C" void kernel_launch(void* const* d_in, const int* in_sizes, int n_in,
                              void* d_out, int out_size, void* d_ws, size_t ws_size,
                              hipStream_t stream) {
  const float* pred = (const float*)d_in[0];
  const float* gt   = (const float*)d_in[1];
  const float* mask = (const float*)d_in[2];
  float* out = (float*)d_out;
  int n = in_sizes[0];
  int n4 = n / 4;
  char* ws = (char*)d_ws;

  // R22 grid: b=800, S = 800*256 = 204800. n4 = 16S for 32x640x640.
  // Chunks (in 4S groups): chunk1 = 4S, chunk2 = 4S, chunk3 = (q-2)*4S,
  // each a pointer-shifted launch of the identical kernel. Remainder (generic
  // n only) -> k2_tail.
  const int B1 = 800;
  const int S1 = B1 * 256;
  const int G = 4 * S1;                 // one 4-step group = 819200 float4
  int q = n4 / G;                       // full groups (4 for this shape)
  int nchunks = 0;
  int clen[3] = {0, 0, 0};
  if (q >= 4) { nchunks = 3; clen[0] = G; clen[1] = G; clen[2] = (q - 2) * G; }
  else if (q >= 1) { nchunks = 1; clen[0] = q * G; }
  int covered = (nchunks ? (clen[0] + clen[1] + clen[2]) : 0);
  int need_tail = (covered != n4) || ((n & 3) != 0);
  const int TAILB = 256;
  int nwaves = B1 * 4 * nchunks + (need_tail ? TAILB * 4 : 0);

  // layout: hist1@256 (16KB) -> zero first 16640B; wredux@64KB (~154KB max)
  const size_t HIST1_OFF = 256;
  const size_t ZERO_BYTES = HIST1_OFF + NBINS1 * sizeof(unsigned);   // 16640
  const size_t WREDUX_OFF = 64 * 1024;

  unsigned* hist1 = (unsigned*)(ws + HIST1_OFF);
  float4* wredux = (float4*)(ws + WREDUX_OFF);

  hipMemsetAsync(d_ws, 0, ZERO_BYTES, stream);
  int start4 = 0;
  for (int c = 0; c < nchunks; ++c) {
    // pointer-shift by chunk start (in floats = 4 * float4 index)
    k1_hist<<<B1, 256, 0, stream>>>(pred + (size_t)4 * start4,
                                    gt + (size_t)4 * start4,
                                    mask + (size_t)4 * start4,
                                    hist1, wredux + (size_t)B1 * 4 * c, clen[c]);
    start4 += clen[c];
  }
  if (need_tail) {
    k2_tail<<<TAILB, 256, 0, stream>>>(pred, gt, mask, hist1, wredux,
                                       covered, n4, n, B1 * 4 * nchunks);
  }
  k5_final<<<1, 256, 0, stream>>>(hist1, wredux, nwaves, out);
}

// Round 13
// 179.719 us; speedup vs baseline: 1.1835x; 1.1835x over previous
//
#include <hip/hip_runtime.h>
#include <math.h>

// MaskedBalancedBCELoss — hard-negative mining via count-histogram select.
//
// R23: LOCK-IN round — revert to the best harness-verified config (R20,
// 181.4us total, k1=61.7us). Kernels byte-identical to R20/R21/R22.
// Session conclusion (R15-R22 ablation arc):
//   * The original 75us wall was the divergent branch around the LDS atomic
//     (R16): branchless unconditional atomicAdd fixed it.
//   * The remaining k1 time (61.7us = 157MB @ 2.55 TB/s) is pinned by the
//     harness protocol, not structure: every first-position heavy kernel
//     runs at ~2.6 TB/s (~10.3 B/cy/CU at unramped clock); the SAME code
//     late in a busy window hits 6.35 TB/s (R16 k1b: 24.7us/pass), and the
//     harness's own fill kernels hit 6.6 TB/s back-to-back (R22).
//   * Balance (R21: b=1024 -> no change) and kernel-boundary chunking
//     (R22: 3 pointer-shifted launches -> null + launch overhead) both
//     falsified non-clock explanations.
// Structural floor: 157MB mandatory read / 2.6 TB/s protocol BW ~= 60us;
// k1 is within a few percent. Remaining ~115us of total is harness-fixed
// (R14 single-dispatch bound: ~86us + memset + k5).
// Expect k1 ~61-62, total ~181. Declare <<ROOFLINE>> next round on repro.

#define NBINS1 4096

#define LN2F 0.69314718055994530942f

__device__ __forceinline__ double bin_mid(unsigned b) {
  return (double)__uint_as_float((b << 19) | 0x40000u);
}

// Branchless per-element processing (loss bit-identical to R10..R22).
__device__ __forceinline__ void proc1(float p, float g, float m, unsigned ln,
                                      unsigned& pc, unsigned& nc,
                                      float& psumf, unsigned* __restrict__ hc) {
  bool gpos = (g != 0.0f);
  bool valid = (m != 0.0f);
  bool ispos = valid && gpos;
  bool isneg = valid && !gpos;
  float x = gpos ? p : 1.0f - p;
  float loss = -fmaxf(__log2f(x) * LN2F, -100.0f);
  pc += ispos ? 1u : 0u;
  nc += isneg ? 1u : 0u;
  psumf += ispos ? loss : 0.0f;
  unsigned b = isneg ? (__float_as_uint(loss) >> 19) : (NBINS1 + ln);
  atomicAdd(&hc[b], 1u);
}

// ---------------- Kernel 1: dg_kb1-shaped hot kernel -----------------------
// Covers [0, nfull4) float4s exactly (host guarantees nfull4 % (4*S) == 0).
// NOTHING else lives in this kernel. Do not add code here.
extern "C" __global__ void __launch_bounds__(256, 4)
k1_hist(const float* __restrict__ pred, const float* __restrict__ gt,
        const float* __restrict__ mask, unsigned* __restrict__ hist1,
        float4* __restrict__ wredux, int nfull4) {
  __shared__ unsigned h[NBINS1 + 64];
  for (int i = threadIdx.x; i < NBINS1 + 64; i += blockDim.x) h[i] = 0u;
  __syncthreads();

  const float4* p4 = (const float4*)pred;
  const float4* g4 = (const float4*)gt;
  const float4* m4 = (const float4*)mask;
  int gtid = blockIdx.x * blockDim.x + threadIdx.x;
  int S = gridDim.x * blockDim.x;
  unsigned ln = threadIdx.x & 63;

  unsigned pc = 0, nc = 0;
  float psumf = 0.0f;
  for (int rep = 0; rep < 1; ++rep) {
    for (int i = gtid; i + 3 * S < nfull4; i += 4 * S) {
      int jb = i + rep;
      float4 pv0 = p4[jb], pv1 = p4[jb + S], pv2 = p4[jb + 2 * S], pv3 = p4[jb + 3 * S];
      float4 gv0 = g4[jb], gv1 = g4[jb + S], gv2 = g4[jb + 2 * S], gv3 = g4[jb + 3 * S];
      float4 mv0 = m4[jb], mv1 = m4[jb + S], mv2 = m4[jb + 2 * S], mv3 = m4[jb + 3 * S];
      float pa[16] = {pv0.x, pv0.y, pv0.z, pv0.w, pv1.x, pv1.y, pv1.z, pv1.w,
                      pv2.x, pv2.y, pv2.z, pv2.w, pv3.x, pv3.y, pv3.z, pv3.w};
      float ga[16] = {gv0.x, gv0.y, gv0.z, gv0.w, gv1.x, gv1.y, gv1.z, gv1.w,
                      gv2.x, gv2.y, gv2.z, gv2.w, gv3.x, gv3.y, gv3.z, gv3.w};
      float ma[16] = {mv0.x, mv0.y, mv0.z, mv0.w, mv1.x, mv1.y, mv1.z, mv1.w,
                      mv2.x, mv2.y, mv2.z, mv2.w, mv3.x, mv3.y, mv3.z, mv3.w};
#pragma unroll
      for (int j = 0; j < 16; j++) {
        bool gpos = (ga[j] != 0.0f);
        bool valid = (ma[j] != 0.0f);
        bool ispos = valid && gpos;
        bool isneg = valid && !gpos;
        float x = gpos ? pa[j] : 1.0f - pa[j];
        float loss = -fmaxf(__log2f(x) * LN2F, -100.0f);
        pc += ispos ? 1u : 0u;
        nc += isneg ? 1u : 0u;
        psumf += ispos ? loss : 0.0f;
        unsigned b = isneg ? (__float_as_uint(loss) >> 19) : (NBINS1 + ln);
        atomicAdd(&h[b], 1u);   // unconditional: no exec-mask branch
      }
    }
  }

  // epilogue, dg_kb1-shaped: f32 shuffle reduce + ONE plain store per wave.
  // counts <= 4096/wave -> exact in f32.
  float fpc = (float)pc, fnc = (float)nc;
  for (int off = 32; off > 0; off >>= 1) {
    fpc += __shfl_down(fpc, off);
    fnc += __shfl_down(fnc, off);
    psumf += __shfl_down(psumf, off);
  }
  if (ln == 0)
    wredux[blockIdx.x * 4 + (threadIdx.x >> 6)] = make_float4(fpc, fnc, psumf, 0.0f);
  __syncthreads();   // all LDS histogram atomics complete
  for (int b = threadIdx.x; b < NBINS1; b += blockDim.x) {
    unsigned c = h[b];
    if (c) atomicAdd(&hist1[b], c);
  }
}

// -------- k2_tail: cold coverage for generic n (NOT launched when the ------
// divisor search succeeds and n%4==0, i.e. never for 32x640x640).
extern "C" __global__ void __launch_bounds__(256, 4)
k2_tail(const float* __restrict__ pred, const float* __restrict__ gt,
        const float* __restrict__ mask, unsigned* __restrict__ hist1,
        float4* __restrict__ wredux, int start4, int n4, int n, int wbase) {
  __shared__ unsigned h[NBINS1 + 64];
  for (int i = threadIdx.x; i < NBINS1 + 64; i += blockDim.x) h[i] = 0u;
  __syncthreads();

  const float4* p4 = (const float4*)pred;
  const float4* g4 = (const float4*)gt;
  const float4* m4 = (const float4*)mask;
  int gtid = blockIdx.x * blockDim.x + threadIdx.x;
  int S = gridDim.x * blockDim.x;
  unsigned ln = threadIdx.x & 63;

  unsigned pc = 0, nc = 0;
  float psumf = 0.0f;
  for (int i = start4 + gtid; i < n4; i += S) {
    float4 pv = p4[i], gv = g4[i], mv = m4[i];
    proc1(pv.x, gv.x, mv.x, ln, pc, nc, psumf, h);
    proc1(pv.y, gv.y, mv.y, ln, pc, nc, psumf, h);
    proc1(pv.z, gv.z, mv.z, ln, pc, nc, psumf, h);
    proc1(pv.w, gv.w, mv.w, ln, pc, nc, psumf, h);
  }
  for (int t = n4 * 4 + gtid; t < n; t += S) {
    proc1(pred[t], gt[t], mask[t], ln, pc, nc, psumf, h);
  }

  float fpc = (float)pc, fnc = (float)nc;
  for (int off = 32; off > 0; off >>= 1) {
    fpc += __shfl_down(fpc, off);
    fnc += __shfl_down(fnc, off);
    psumf += __shfl_down(psumf, off);
  }
  if (ln == 0)
    wredux[wbase + blockIdx.x * 4 + (threadIdx.x >> 6)] = make_float4(fpc, fnc, psumf, 0.0f);
  __syncthreads();
  for (int b = threadIdx.x; b < NBINS1; b += blockDim.x) {
    unsigned c = h[b];
    if (c) atomicAdd(&hist1[b], c);
  }
}

// ---------- Kernel 5: wredux reduce + select + midpoint neg_sum ------------
extern "C" __global__ void __launch_bounds__(256)
k5_final(const unsigned* __restrict__ hist1, const float4* __restrict__ wredux,
         int nwaves, float* __restrict__ out) {
  const int T = 256, CH = NBINS1 / T;  // 16 bins per thread
  __shared__ unsigned long long sarr[T];
  __shared__ unsigned long long sk;
  __shared__ unsigned sB, skrem;
  __shared__ double sred[4];
  __shared__ double rpc[T], rnc[T], rps[T];
  __shared__ unsigned long long s_pos;
  __shared__ double s_psum;
  int t = threadIdx.x;
  int wv = t >> 6, ln = t & 63;

  // ---- reduce per-wave partials (exact: counts are integers in f32) ----
  double tpc = 0.0, tnc = 0.0, tps = 0.0;
  for (int i = t; i < nwaves; i += T) {
    float4 v = wredux[i];
    tpc += (double)v.x; tnc += (double)v.y; tps += (double)v.z;
  }
  rpc[t] = tpc; rnc[t] = tnc; rps[t] = tps;
  __syncthreads();
  for (int off = T / 2; off > 0; off >>= 1) {
    if (t < off) { rpc[t] += rpc[t + off]; rnc[t] += rnc[t + off]; rps[t] += rps[t + off]; }
    __syncthreads();
  }

  unsigned cnt[CH];
  unsigned long long tot = 0;
  for (int j = 0; j < CH; j++) { cnt[j] = hist1[t * CH + j]; tot += cnt[j]; }
  sarr[t] = tot;
  if (t == 0) {
    sB = 0xFFFFFFFFu; skrem = 0u;
    unsigned long long pos = (unsigned long long)(rpc[0] + 0.5);
    unsigned long long negtot = (unsigned long long)(rnc[0] + 0.5);
    unsigned long long k = 0;
    if (pos > 0) {               // FALLBACK_NEG=0 when pos==0
      k = pos * 3ull;            // floor(pos*3.0), exact in integer
      if (k > negtot) k = negtot;
    }
    sk = k;
    s_pos = pos;
    s_psum = rps[0];
  }
  __syncthreads();
  // inclusive suffix scan: sarr[t] = sum over threads >= t
  for (int off = 1; off < T; off <<= 1) {
    unsigned long long v = (t + off < T) ? sarr[t + off] : 0ull;
    __syncthreads();
    sarr[t] += v;
    __syncthreads();
  }
  unsigned long long k = sk;
  if (k > 0) {
    unsigned long long above = sarr[t] - tot;
    if (above < k && sarr[t] >= k) {
      unsigned long long cum = above;
      for (int j = CH - 1; j >= 0; j--) {
        if (cum + (unsigned long long)cnt[j] >= k) {
          sB = (unsigned)(t * CH + j);
          skrem = (unsigned)(k - cum);
          break;
        }
        cum += cnt[j];
      }
    }
  }
  __syncthreads();
  unsigned B = sB;

  // neg_sum (midpoint model): each thread sums its own bins above B
  double s = 0.0;
  if (B != 0xFFFFFFFFu) {
    for (int j = 0; j < CH; j++) {
      unsigned bi = (unsigned)(t * CH + j);
      if (bi > B && cnt[j]) s += (double)cnt[j] * bin_mid(bi);
    }
  }
  for (int off = 32; off > 0; off >>= 1) s += __shfl_down(s, off);
  if (ln == 0) sred[wv] = s;
  __syncthreads();
  if (t == 0) {
    double neg_sum = sred[0] + sred[1] + sred[2] + sred[3];
    if (skrem > 0 && B != 0xFFFFFFFFu)
      neg_sum += (double)skrem * bin_mid(B);
    double denom = (double)s_pos + (double)k + 1e-6;
    out[0] = (float)((s_psum + neg_sum) / denom);
  }
}

// ---------------------------------------------------------------------------
extern "C" void kernel_launch(void* const* d_in, const int* in_sizes, int n_in,
                              void* d_out, int out_size, void* d_ws, size_t ws_size,
                              hipStream_t stream) {
  const float* pred = (const float*)d_in[0];
  const float* gt   = (const float*)d_in[1];
  const float* mask = (const float*)d_in[2];
  float* out = (float*)d_out;
  int n = in_sizes[0];
  int n4 = n / 4;
  char* ws = (char*)d_ws;

  // R20 grid choice (best measured): largest b in [256,1024] with
  // n4 % (b*1024) == 0 -> EXACT coverage, single k1, no tail.
  // 32x640x640 -> b=800, 4 iters/thread.
  int b = 0;
  for (int cand = 1024; cand >= 256; --cand) {
    if (n4 % (cand * 1024) == 0) { b = cand; break; }
  }
  int nfull4, need_tail;
  if (b > 0) {
    nfull4 = n4;
    need_tail = (n & 3) != 0;
  } else {
    b = 1024;
    nfull4 = (n4 / (b * 1024)) * (b * 1024);
    need_tail = 1;
  }
  const int TAILB = 256;
  int nwaves = b * 4 + (need_tail ? TAILB * 4 : 0);

  // layout: hist1@256 (16KB) -> zero first 16640B; wredux@64KB
  const size_t HIST1_OFF = 256;
  const size_t ZERO_BYTES = HIST1_OFF + NBINS1 * sizeof(unsigned);   // 16640
  const size_t WREDUX_OFF = 64 * 1024;

  unsigned* hist1 = (unsigned*)(ws + HIST1_OFF);
  float4* wredux = (float4*)(ws + WREDUX_OFF);

  hipMemsetAsync(d_ws, 0, ZERO_BYTES, stream);
  k1_hist<<<b, 256, 0, stream>>>(pred, gt, mask, hist1, wredux, nfull4);
  if (need_tail) {
    k2_tail<<<TAILB, 256, 0, stream>>>(pred, gt, mask, hist1, wredux,
                                       nfull4, n4, n, b * 4);
  }
  k5_final<<<1, 256, 0, stream>>>(hist1, wredux, nwaves, out);
}